// Round 6
// baseline (305.112 us; speedup 1.0000x reference)
//
#include <hip/hip_runtime.h>
#include <hip/hip_fp16.h>
#include <hip/hip_cooperative_groups.h>

namespace cg = cooperative_groups;

#define B_ 256
#define N_ 192
#define D_ 512
#define E_ 1024
#define H_ 512
#define K_ 58
#define M_ (B_*K_)      // 14848 real rows
#define M2_ (B_*64)     // 16384 padded rows (64 per batch, rows 58-63 zero)

typedef _Float16 f16;
typedef unsigned int u32;
typedef _Float16 half8 __attribute__((ext_vector_type(8)));
typedef float floatx16 __attribute__((ext_vector_type(16)));

#define WAIT_VMCNT0() asm volatile("s_waitcnt vmcnt(0)" ::: "memory")
#define BAR()         __builtin_amdgcn_s_barrier()
#define PRIO1()       __builtin_amdgcn_s_setprio(1)
#define PRIO0()       __builtin_amdgcn_s_setprio(0)

__device__ inline half8 cvt8(float4 f0, float4 f1) {
  half8 r;
  r[0]=(f16)f0.x; r[1]=(f16)f0.y; r[2]=(f16)f0.z; r[3]=(f16)f0.w;
  r[4]=(f16)f1.x; r[5]=(f16)f1.y; r[6]=(f16)f1.z; r[7]=(f16)f1.w;
  return r;
}

// async global->LDS, 16B/lane; LDS dest = wave-uniform base + lane*16
__device__ inline void gl_lds16(const f16* g, f16* l) {
  __builtin_amdgcn_global_load_lds((const __attribute__((address_space(1))) u32*)g,
                                   (__attribute__((address_space(3))) u32*)l, 16, 0, 0);
}

// ---- 128x32 tile stage (gemm1, 4-chunk swizzle: slot c' holds chunk c'^((r>>1)&3)) ----
__device__ inline void stage128(const f16* gbase, int gstride, f16* sT, int w, int lane) {
  int lrow  = lane >> 2;
  int chunk = (lane & 3) ^ ((lane >> 3) & 3);
  gl_lds16(gbase + (size_t)(w*16      + lrow)*gstride + chunk*8, &sT[(w*16)*32]);
  gl_lds16(gbase + (size_t)(64 + w*16 + lrow)*gstride + chunk*8, &sT[(64 + w*16)*32]);
}

// ---- 128x64 half-tile stage (fused 256x64 tiles, 8-chunk swizzle) ----
// Row stride 64 f16 = 128B.  LDS slot (r, c') holds global chunk c = c' ^ (r&7).
// Lane l: row lrow = l>>3, slot l&7, global chunk (l&7)^lrow.  2 gl_lds/wave.
__device__ inline void stage_half(const f16* gbase, f16* sT, int h, int w, int lane) {
  int lrow = lane >> 3;              // 0..7
  int cg   = (lane & 7) ^ lrow;      // global chunk
  int r0 = h*128 + w*16;
  gl_lds16(gbase + (size_t)(r0     + lrow)*1024 + cg*8, &sT[(size_t)r0*64]);
  gl_lds16(gbase + (size_t)(r0 + 8 + lrow)*1024 + cg*8, &sT[(size_t)(r0 + 8)*64]);
}

// ---------- setup: weight cvt + topk + gather + L2norm + stats-zero ---------
__global__ void setup_kernel(const float* __restrict__ Wfc, const float* __restrict__ W2,
                             const float* __restrict__ W1, const float* __restrict__ attn,
                             const float* __restrict__ emb,
                             f16* __restrict__ Wcat, f16* __restrict__ W1_16,
                             f16* __restrict__ A16, float* __restrict__ csum) {
  __shared__ float sv[N_];
  __shared__ int sidx[K_];
  __shared__ int cnt;
  int blk = blockIdx.x, t = threadIdx.x;
  if (blk < 512) {                      // Wcat = [Wfc;W2]: 1024x1024 f16
    int idx = (blk*256 + t)*8;
    int e = idx >> 10, c = idx & 1023;
    const float* src = (c < 512) ? (Wfc + (size_t)e*512 + c)
                                 : (W2  + (size_t)e*512 + (c-512));
    half8 o = cvt8(((const float4*)src)[0], ((const float4*)src)[1]);
    *(uint4*)(Wcat + idx) = *(uint4*)&o;
  } else if (blk < 640) {               // W1_16: 512x512 f16
    int idx = ((blk-512)*256 + t)*8;
    const float* src = W1 + idx;
    half8 o = cvt8(((const float4*)src)[0], ((const float4*)src)[1]);
    *(uint4*)(W1_16 + idx) = *(uint4*)&o;
  } else if (blk < 896) {               // topk + gather + L2norm for batch b
    int b = blk - 640;
    if (t == 0) cnt = 0;
    if (t < N_) sv[t] = attn[(size_t)b*193*193 + 1 + t];
    __syncthreads();
    if (t < N_) {
      float v = sv[t]; int rank = 0;
      for (int j = 0; j < N_; ++j) {
        float vj = sv[j];
        rank += (vj > v) || (vj == v && j < t);   // lax.top_k stable tie-break
      }
      if (rank < K_) sidx[atomicAdd(&cnt, 1)] = t;  // slot order irrelevant (max/BN invariant)
    }
    __syncthreads();
    int w = t >> 6, lane = t & 63;
    for (int slot = w; slot < 64; slot += 4) {
      f16* dst = A16 + ((size_t)b*64 + slot)*1024 + lane*8;
      if (slot < K_) {
        const float* src = emb + ((size_t)b*N_ + sidx[slot])*D_ + lane*8;
        float4 v0 = ((const float4*)src)[0];
        float4 v1 = ((const float4*)src)[1];
        float s = v0.x*v0.x + v0.y*v0.y + v0.z*v0.z + v0.w*v0.w
                + v1.x*v1.x + v1.y*v1.y + v1.z*v1.z + v1.w*v1.w;
        #pragma unroll
        for (int off = 32; off > 0; off >>= 1) s += __shfl_xor(s, off);
        float inv = 1.0f / (sqrtf(s) + 1e-8f);
        half8 o;
        o[0]=(f16)(v0.x*inv); o[1]=(f16)(v0.y*inv); o[2]=(f16)(v0.z*inv); o[3]=(f16)(v0.w*inv);
        o[4]=(f16)(v1.x*inv); o[5]=(f16)(v1.y*inv); o[6]=(f16)(v1.z*inv); o[7]=(f16)(v1.w*inv);
        *(uint4*)dst = *(uint4*)&o;
      } else {
        uint4 z; z.x=0u; z.y=0u; z.z=0u; z.w=0u;
        *(uint4*)dst = z;   // pad rows zero
      }
    }
  } else {                              // zero csum(512)+css(512), contiguous
    float4 z; z.x=0.f; z.y=0.f; z.z=0.f; z.w=0.f;
    ((float4*)csum)[t] = z;
  }
}

// ---------- gemm1 (COOPERATIVE): h = A@W1^T + b1; stats; grid.sync();
//            then BN+relu applied to the in-register acc; write post-BN h ----
// 512 blocks @ __launch_bounds__(256,2) = exactly co-resident on 256 CUs,
// so hipLaunchCooperativeKernel grid sync is capacity-safe.  Removes the
// separate bnrelu pass (33.5 MB r/w) entirely; h is written exactly once.
__launch_bounds__(256, 2)
__global__ void gemm1_kernel(const f16* __restrict__ A16, const f16* __restrict__ W1_16,
                             const float* __restrict__ b1, f16* __restrict__ Aout,
                             float* __restrict__ csum, float* __restrict__ css,
                             const float* __restrict__ gamma, const float* __restrict__ beta) {
  __shared__ f16 sA[2][128*32];
  __shared__ f16 sB[2][128*32];
  __shared__ float sSum[4][64], sSS[4][64];
  int t = threadIdx.x;
  int g = blockIdx.x;                   // 512 blocks: xcd-swizzled
  int xcd = g & 7, rest = g >> 3;
  int n0 = (rest & 3) * 128;            // 4 n-tiles
  int m0 = (xcd + 8*(rest >> 2)) * 128; // same-m blocks same XCD
  int lane = t & 63, w = t >> 6;
  int l31 = lane & 31, khalf = lane >> 5, swz = (l31 >> 1) & 3;
  int rw = w & 1, cw = w >> 1;          // wave -> 64-row half x 64-col half
  floatx16 acc[2][2] = {};
  const f16* Ab = A16 + (size_t)m0*1024;       // left half (cols 0..511)
  const f16* Bb = W1_16 + (size_t)n0*512;
  stage128(Ab, 1024, sA[0], w, lane);
  stage128(Bb, 512,  sB[0], w, lane);
  __syncthreads();
  for (int it = 0; it < 16; ++it) {
    int cur = it & 1, nxt = cur ^ 1;
    if (it < 15) {
      stage128(Ab + (it+1)*32, 1024, sA[nxt], w, lane);
      stage128(Bb + (it+1)*32, 512,  sB[nxt], w, lane);
    }
    #pragma unroll
    for (int s = 0; s < 2; ++s) {       // two K=16 steps per 32-wide buffer
      int ko = ((s*2 + khalf) ^ swz) * 8;
      half8 a[2], bf[2];
      #pragma unroll
      for (int i = 0; i < 2; ++i) a[i]  = *(const half8*)&sA[cur][(rw*64 + i*32 + l31)*32 + ko];
      #pragma unroll
      for (int j = 0; j < 2; ++j) bf[j] = *(const half8*)&sB[cur][(cw*64 + j*32 + l31)*32 + ko];
      #pragma unroll
      for (int i = 0; i < 2; ++i)
        #pragma unroll
        for (int j = 0; j < 2; ++j)
          acc[i][j] = __builtin_amdgcn_mfma_f32_32x32x16_f16(a[i], bf[j], acc[i][j], 0, 0, 0);
    }
    __syncthreads();
  }
  // stats: masked column sums of x = acc + bias over real rows
  // C/D: col = l31, row = (reg&3) + 8*(reg>>2) + 4*khalf  (within 32x32 tile)
  #pragma unroll
  for (int jt = 0; jt < 2; ++jt) {
    int col = n0 + cw*64 + jt*32 + l31;
    float bias = b1[col];
    float s = 0.f, ss = 0.f;
    #pragma unroll
    for (int i = 0; i < 2; ++i) {
      #pragma unroll
      for (int rg = 0; rg < 16; ++rg) {
        int rib = i*32 + (rg&3) + 8*(rg>>2) + 4*khalf;   // row within batch (0..63)
        float x = acc[i][jt][rg] + bias;
        if (i == 0 || rib < K_) { s += x; ss += x*x; }
      }
    }
    s  += __shfl_xor(s, 32);
    ss += __shfl_xor(ss, 32);
    if (lane < 32) { sSum[w][jt*32 + l31] = s; sSS[w][jt*32 + l31] = ss; }
  }
  __syncthreads();
  if (t < 128) {
    int c = t;
    int w0 = 2*(c >> 6), ci = c & 63;
    atomicAdd(&csum[n0 + c], sSum[w0][ci] + sSum[w0+1][ci]);
    atomicAdd(&css[n0 + c],  sSS[w0][ci]  + sSS[w0+1][ci]);
  }
  // ---- grid-wide sync: all blocks' stats atomics complete + visible ----
  cg::this_grid().sync();
  // ---- BN + relu on the in-register acc; write post-BN h (pad rows 0) ----
  #pragma unroll
  for (int jt = 0; jt < 2; ++jt) {
    int col = n0 + cw*64 + jt*32 + l31;
    float bias = b1[col];
    float mu  = csum[col] * (1.0f/M_);
    float var = css[col] * (1.0f/M_) - mu*mu;
    float sc  = gamma[col] * rsqrtf(var + 1e-5f);
    float sh  = beta[col] - mu*sc;
    #pragma unroll
    for (int i = 0; i < 2; ++i) {
      #pragma unroll
      for (int rg = 0; rg < 16; ++rg) {
        int rib = i*32 + (rg&3) + 8*(rg>>2) + 4*khalf;
        float x = acc[i][jt][rg] + bias;
        float y = fmaxf(x*sc + sh, 0.f);
        if (!(i == 0 || rib < K_)) y = 0.f;     // zero pad rows
        Aout[(size_t)(m0 + rw*64 + rib)*1024 + 512 + col] = (f16)y;
      }
    }
  }
}

// ---------- fused: C = A16 @ Wcat^T, max over k, + biases (8-wave 256x256) ---
// 256x256 tile, BK=64, 8 waves (2M x 4N), wave tile 128x64 (acc[4][2] 32x32).
// LDS 132KB -> 1 block/CU, 256 blocks = full chip.  Phase-split schedule:
// 4 phases/K-tile {ds_read subtile || stage -> bar -> setprio(1) 8 MFMA
// setprio(0) -> bar}.  Staging shifted EARLY (A-h0@P1, A-h1+B-h0@P2,
// B-h1@P3, none@P4) so the newest load has ~2 MFMA clusters of latency
// cover at the single iter-end vmcnt(0) drain (1 block/CU -> no TLP cover).
__launch_bounds__(512, 2)
__global__ void fused_kernel(const f16* __restrict__ A16, const f16* __restrict__ Wcat,
                             const float* __restrict__ bfc, const float* __restrict__ b2,
                             float* __restrict__ out) {
  __shared__ __align__(16) f16 sA[2][256*64];   // 64 KB
  __shared__ __align__(16) f16 sB[2][256*64];   // 64 KB
  __shared__ float sMax[4][256];                // 4 KB
  int t = threadIdx.x;
  int g = blockIdx.x;                   // 256 blocks: xcd-swizzled
  int xcd = g & 7, rest = g >> 3;
  int nt = rest & 3;                    // 4 e-tiles of 256
  int bt = xcd + 8*(rest >> 2);         // m-tile 0..63 (4 batches each); same-bt same XCD
  int e0 = nt * 256;
  int lane = t & 63, w = t >> 6;
  int l31 = lane & 31, khalf = lane >> 5, swzr = l31 & 7;
  int wm = w >> 2, wn = w & 3;          // wave tile: rows wm*128+, cols wn*64+
  floatx16 acc[4][2] = {};
  const f16* Ab = A16 + (size_t)bt*256*1024;
  const f16* Bb = Wcat + (size_t)e0*1024;
  // LDS read bases (f16 offsets); slot for k-chunk ck is (ck ^ swzr)
  int aBase0 = (wm*128 +  0 + l31)*64;
  int aBase1 = (wm*128 + 32 + l31)*64;
  int aBase2 = (wm*128 + 64 + l31)*64;
  int aBase3 = (wm*128 + 96 + l31)*64;
  int bBase0 = (wn*64  +  0 + l31)*64;
  int bBase1 = (wn*64  + 32 + l31)*64;
  // prologue: tile 0, all 4 halves
  stage_half(Ab, sA[0], 0, w, lane);
  stage_half(Ab, sA[0], 1, w, lane);
  stage_half(Bb, sB[0], 0, w, lane);
  stage_half(Bb, sB[0], 1, w, lane);
  WAIT_VMCNT0(); BAR();
  int cur = 0;
  #pragma unroll 1
  for (int it = 0; it < 16; ++it) {
    int nxt = cur ^ 1;
    const f16* An = Ab + (it+1)*64;
    const f16* Bn = Bb + (it+1)*64;
    const f16* sAc = sA[cur];
    const f16* sBc = sB[cur];
    half8 a0f[4], a1f[4], a2f[4], a3f[4], b0v[4], b1v[4];
    // ---- P1: read a(mf0,mf1)+b(nf0); stage A-half0; MFMA Q(m-lo, n0) ----
    #pragma unroll
    for (int s = 0; s < 4; ++s) {
      int ko = (((s<<1)|khalf) ^ swzr) << 3;
      a0f[s] = *(const half8*)&sAc[aBase0 + ko];
      a1f[s] = *(const half8*)&sAc[aBase1 + ko];
      b0v[s] = *(const half8*)&sBc[bBase0 + ko];
    }
    if (it < 15) stage_half(An, sA[nxt], 0, w, lane);
    BAR(); PRIO1();
    #pragma unroll
    for (int s = 0; s < 4; ++s) {
      acc[0][0] = __builtin_amdgcn_mfma_f32_32x32x16_f16(a0f[s], b0v[s], acc[0][0], 0,0,0);
      acc[1][0] = __builtin_amdgcn_mfma_f32_32x32x16_f16(a1f[s], b0v[s], acc[1][0], 0,0,0);
    }
    PRIO0(); BAR();
    // ---- P2: read b(nf1); stage A-half1 + B-half0; MFMA Q(m-lo, n1) ----
    #pragma unroll
    for (int s = 0; s < 4; ++s) {
      int ko = (((s<<1)|khalf) ^ swzr) << 3;
      b1v[s] = *(const half8*)&sBc[bBase1 + ko];
    }
    if (it < 15) {
      stage_half(An, sA[nxt], 1, w, lane);
      stage_half(Bn, sB[nxt], 0, w, lane);
    }
    BAR(); PRIO1();
    #pragma unroll
    for (int s = 0; s < 4; ++s) {
      acc[0][1] = __builtin_amdgcn_mfma_f32_32x32x16_f16(a0f[s], b1v[s], acc[0][1], 0,0,0);
      acc[1][1] = __builtin_amdgcn_mfma_f32_32x32x16_f16(a1f[s], b1v[s], acc[1][1], 0,0,0);
    }
    PRIO0(); BAR();
    // ---- P3: read a(mf2,mf3); stage B-half1; MFMA Q(m-hi, n1) ----
    #pragma unroll
    for (int s = 0; s < 4; ++s) {
      int ko = (((s<<1)|khalf) ^ swzr) << 3;
      a2f[s] = *(const half8*)&sAc[aBase2 + ko];
      a3f[s] = *(const half8*)&sAc[aBase3 + ko];
    }
    if (it < 15) stage_half(Bn, sB[nxt], 1, w, lane);
    BAR(); PRIO1();
    #pragma unroll
    for (int s = 0; s < 4; ++s) {
      acc[2][1] = __builtin_amdgcn_mfma_f32_32x32x16_f16(a2f[s], b1v[s], acc[2][1], 0,0,0);
      acc[3][1] = __builtin_amdgcn_mfma_f32_32x32x16_f16(a3f[s], b1v[s], acc[3][1], 0,0,0);
    }
    PRIO0(); BAR();
    // ---- P4: no staging; MFMA Q(m-hi, n0); iter-end drain ----
    BAR(); PRIO1();
    #pragma unroll
    for (int s = 0; s < 4; ++s) {
      acc[2][0] = __builtin_amdgcn_mfma_f32_32x32x16_f16(a2f[s], b0v[s], acc[2][0], 0,0,0);
      acc[3][0] = __builtin_amdgcn_mfma_f32_32x32x16_f16(a3f[s], b0v[s], acc[3][0], 0,0,0);
    }
    PRIO0();
    WAIT_VMCNT0();                     // newest stage (B-h1, P3) ~2 clusters old
    BAR();                             // publish; also retires all reads of slot cur
    cur = nxt;
  }
  // epilogue: masked max over 58 real rows of each batch this wave covers
  // C/D 32x32: col = l31, rowin = (rg&3) + 8*(rg>>2) + 4*khalf
  #pragma unroll
  for (int p = 0; p < 2; ++p) {         // batch = wm*2 + p ; frags mf = 2p, 2p+1
    #pragma unroll
    for (int nf = 0; nf < 2; ++nf) {
      float mx = -3.0e38f;
      #pragma unroll
      for (int rg = 0; rg < 16; ++rg)   // mf even: rows 0..31 all < K_
        mx = fmaxf(mx, acc[2*p][nf][rg]);
      #pragma unroll
      for (int rg = 0; rg < 16; ++rg) { // mf odd: rows 32+rowin, need rowin < 26
        int rowin = (rg&3) + 8*(rg>>2) + 4*khalf;
        if (rowin < K_ - 32) mx = fmaxf(mx, acc[2*p+1][nf][rg]);
      }
      mx = fmaxf(mx, __shfl_xor(mx, 32));
      if (lane < 32) sMax[wm*2 + p][wn*64 + nf*32 + l31] = mx;
    }
  }
  __syncthreads();
  #pragma unroll
  for (int j = 0; j < 2; ++j) {
    int idx = t + j*512;                // 1024 outputs: 4 batches x 256 cols
    int bq = idx >> 8, c = idx & 255;
    int e = e0 + c;
    out[((size_t)bt*4 + bq)*E_ + e] = sMax[bq][c] + bfc[e] + b2[e];
  }
}

extern "C" void kernel_launch(void* const* d_in, const int* in_sizes, int n_in,
                              void* d_out, int out_size, void* d_ws, size_t ws_size,
                              hipStream_t stream) {
  const float* emb   = (const float*)d_in[0];
  const float* attn  = (const float*)d_in[1];
  const float* Wfc   = (const float*)d_in[2];
  const float* bfc   = (const float*)d_in[3];
  const float* W1    = (const float*)d_in[4];
  const float* b1    = (const float*)d_in[5];
  const float* gamma = (const float*)d_in[6];
  const float* beta  = (const float*)d_in[7];
  const float* W2    = (const float*)d_in[8];
  const float* b2    = (const float*)d_in[9];
  float* out = (float*)d_out;

  char* ws = (char*)d_ws;
  f16*   A16   = (f16*)(ws);                    // 16384*1024*2 = 33,554,432
  f16*   Wcat  = (f16*)(ws + 33554432);         // 1024*1024*2  =  2,097,152
  f16*   W1_16 = (f16*)(ws + 35651584);         //  512*512*2   =    524,288
  float* csum  = (float*)(ws + 36175872);       // 2048
  float* css   = (float*)(ws + 36177920);       // 2048 (contiguous after csum)

  setup_kernel<<<897, 256, 0, stream>>>(Wfc, W2, W1, attn, emb, Wcat, W1_16, A16, csum);

  // cooperative gemm1: 512 blocks x 256 thr @ (256,2) -> exactly co-resident
  const f16* A16c = A16;
  const f16* W1c  = W1_16;
  f16* A16o = A16;
  float* csumv = csum; float* cssv = css;
  const float* b1c = b1; const float* gammac = gamma; const float* betac = beta;
  void* gargs[8];
  gargs[0] = (void*)&A16c;  gargs[1] = (void*)&W1c;   gargs[2] = (void*)&b1c;
  gargs[3] = (void*)&A16o;  gargs[4] = (void*)&csumv; gargs[5] = (void*)&cssv;
  gargs[6] = (void*)&gammac; gargs[7] = (void*)&betac;
  hipLaunchCooperativeKernel((const void*)gemm1_kernel, dim3(512), dim3(256),
                             gargs, 0, stream);

  fused_kernel<<<256, 512, 0, stream>>>(A16, Wcat, bfc, b2, out);
}

// Round 7
// 234.624 us; speedup vs baseline: 1.3004x; 1.3004x over previous
//
#include <hip/hip_runtime.h>
#include <hip/hip_fp16.h>

#define B_ 256
#define N_ 192
#define D_ 512
#define E_ 1024
#define H_ 512
#define K_ 58
#define M_ (B_*K_)      // 14848 real rows
#define M2_ (B_*64)     // 16384 padded rows (64 per batch, rows 58-63 zero)

typedef _Float16 f16;
typedef unsigned int u32;
typedef _Float16 half8 __attribute__((ext_vector_type(8)));
typedef float floatx16 __attribute__((ext_vector_type(16)));

#define WAIT_VMCNT0() asm volatile("s_waitcnt vmcnt(0)" ::: "memory")
#define BAR()         __builtin_amdgcn_s_barrier()
#define PRIO1()       __builtin_amdgcn_s_setprio(1)
#define PRIO0()       __builtin_amdgcn_s_setprio(0)

__device__ inline half8 cvt8(float4 f0, float4 f1) {
  half8 r;
  r[0]=(f16)f0.x; r[1]=(f16)f0.y; r[2]=(f16)f0.z; r[3]=(f16)f0.w;
  r[4]=(f16)f1.x; r[5]=(f16)f1.y; r[6]=(f16)f1.z; r[7]=(f16)f1.w;
  return r;
}

// async global->LDS, 16B/lane; LDS dest = wave-uniform base + lane*16
__device__ inline void gl_lds16(const f16* g, f16* l) {
  __builtin_amdgcn_global_load_lds((const __attribute__((address_space(1))) u32*)g,
                                   (__attribute__((address_space(3))) u32*)l, 16, 0, 0);
}

// ---- 128x32 tile stage (gemm1, 4-chunk swizzle: slot c' holds chunk c'^((r>>1)&3)) ----
__device__ inline void stage128(const f16* gbase, int gstride, f16* sT, int w, int lane) {
  int lrow  = lane >> 2;
  int chunk = (lane & 3) ^ ((lane >> 3) & 3);
  gl_lds16(gbase + (size_t)(w*16      + lrow)*gstride + chunk*8, &sT[(w*16)*32]);
  gl_lds16(gbase + (size_t)(64 + w*16 + lrow)*gstride + chunk*8, &sT[(64 + w*16)*32]);
}

// ---- 128x64 half-tile stage (fused 256x64 tiles, 8-chunk swizzle) ----
// Row stride 64 f16 = 128B.  LDS slot (r, c') holds global chunk c = c' ^ (r&7).
// Lane l: row lrow = l>>3, slot l&7, global chunk (l&7)^lrow.  2 gl_lds/wave.
__device__ inline void stage_half(const f16* gbase, f16* sT, int h, int w, int lane) {
  int lrow = lane >> 3;              // 0..7
  int cg   = (lane & 7) ^ lrow;      // global chunk
  int r0 = h*128 + w*16;
  gl_lds16(gbase + (size_t)(r0     + lrow)*1024 + cg*8, &sT[(size_t)r0*64]);
  gl_lds16(gbase + (size_t)(r0 + 8 + lrow)*1024 + cg*8, &sT[(size_t)(r0 + 8)*64]);
}

// ---------- setup: weight cvt + topk + gather + L2norm + stats-zero ---------
__global__ void setup_kernel(const float* __restrict__ Wfc, const float* __restrict__ W2,
                             const float* __restrict__ W1, const float* __restrict__ attn,
                             const float* __restrict__ emb,
                             f16* __restrict__ Wcat, f16* __restrict__ W1_16,
                             f16* __restrict__ A16, float* __restrict__ csum) {
  __shared__ float sv[N_];
  __shared__ int sidx[K_];
  __shared__ int cnt;
  int blk = blockIdx.x, t = threadIdx.x;
  if (blk < 512) {                      // Wcat = [Wfc;W2]: 1024x1024 f16
    int idx = (blk*256 + t)*8;
    int e = idx >> 10, c = idx & 1023;
    const float* src = (c < 512) ? (Wfc + (size_t)e*512 + c)
                                 : (W2  + (size_t)e*512 + (c-512));
    half8 o = cvt8(((const float4*)src)[0], ((const float4*)src)[1]);
    *(uint4*)(Wcat + idx) = *(uint4*)&o;
  } else if (blk < 640) {               // W1_16: 512x512 f16
    int idx = ((blk-512)*256 + t)*8;
    const float* src = W1 + idx;
    half8 o = cvt8(((const float4*)src)[0], ((const float4*)src)[1]);
    *(uint4*)(W1_16 + idx) = *(uint4*)&o;
  } else if (blk < 896) {               // topk + gather + L2norm for batch b
    int b = blk - 640;
    if (t == 0) cnt = 0;
    if (t < N_) sv[t] = attn[(size_t)b*193*193 + 1 + t];
    __syncthreads();
    if (t < N_) {
      float v = sv[t]; int rank = 0;
      for (int j = 0; j < N_; ++j) {
        float vj = sv[j];
        rank += (vj > v) || (vj == v && j < t);   // lax.top_k stable tie-break
      }
      if (rank < K_) sidx[atomicAdd(&cnt, 1)] = t;  // slot order irrelevant (max/BN invariant)
    }
    __syncthreads();
    int w = t >> 6, lane = t & 63;
    for (int slot = w; slot < 64; slot += 4) {
      f16* dst = A16 + ((size_t)b*64 + slot)*1024 + lane*8;
      if (slot < K_) {
        const float* src = emb + ((size_t)b*N_ + sidx[slot])*D_ + lane*8;
        float4 v0 = ((const float4*)src)[0];
        float4 v1 = ((const float4*)src)[1];
        float s = v0.x*v0.x + v0.y*v0.y + v0.z*v0.z + v0.w*v0.w
                + v1.x*v1.x + v1.y*v1.y + v1.z*v1.z + v1.w*v1.w;
        #pragma unroll
        for (int off = 32; off > 0; off >>= 1) s += __shfl_xor(s, off);
        float inv = 1.0f / (sqrtf(s) + 1e-8f);
        half8 o;
        o[0]=(f16)(v0.x*inv); o[1]=(f16)(v0.y*inv); o[2]=(f16)(v0.z*inv); o[3]=(f16)(v0.w*inv);
        o[4]=(f16)(v1.x*inv); o[5]=(f16)(v1.y*inv); o[6]=(f16)(v1.z*inv); o[7]=(f16)(v1.w*inv);
        *(uint4*)dst = *(uint4*)&o;
      } else {
        uint4 z; z.x=0u; z.y=0u; z.z=0u; z.w=0u;
        *(uint4*)dst = z;   // pad rows zero
      }
    }
  } else {                              // zero csum(512)+css(512), contiguous
    float4 z; z.x=0.f; z.y=0.f; z.z=0.f; z.w=0.f;
    ((float4*)csum)[t] = z;
  }
}

// ---------- gemm1: A16[:,512:1024] = A16[:,0:512] @ W1_16^T + b1 + stats ----
// Round-0 proven structure: 128x128 tile, BK=32, dbuf LDS, __syncthreads.
// (Round-6 lesson: cooperative grid.sync costs ~57 us on MI355X — 8 XCD
//  non-coherent L2 release/acquire — never worth replacing a 5.5 us pass.)
__launch_bounds__(256, 2)
__global__ void gemm1_kernel(const f16* __restrict__ A16, const f16* __restrict__ W1_16,
                             const float* __restrict__ b1, f16* __restrict__ Aout,
                             float* __restrict__ csum, float* __restrict__ css) {
  __shared__ f16 sA[2][128*32];
  __shared__ f16 sB[2][128*32];
  __shared__ float sSum[4][64], sSS[4][64];
  int t = threadIdx.x;
  int g = blockIdx.x;                   // 512 blocks: xcd-swizzled
  int xcd = g & 7, rest = g >> 3;
  int n0 = (rest & 3) * 128;            // 4 n-tiles
  int m0 = (xcd + 8*(rest >> 2)) * 128; // same-m blocks same XCD
  int lane = t & 63, w = t >> 6;
  int l31 = lane & 31, khalf = lane >> 5, swz = (l31 >> 1) & 3;
  int rw = w & 1, cw = w >> 1;          // wave -> 64-row half x 64-col half
  floatx16 acc[2][2] = {};
  const f16* Ab = A16 + (size_t)m0*1024;       // left half (cols 0..511)
  const f16* Bb = W1_16 + (size_t)n0*512;
  stage128(Ab, 1024, sA[0], w, lane);
  stage128(Bb, 512,  sB[0], w, lane);
  __syncthreads();
  for (int it = 0; it < 16; ++it) {
    int cur = it & 1, nxt = cur ^ 1;
    if (it < 15) {
      stage128(Ab + (it+1)*32, 1024, sA[nxt], w, lane);
      stage128(Bb + (it+1)*32, 512,  sB[nxt], w, lane);
    }
    #pragma unroll
    for (int s = 0; s < 2; ++s) {       // two K=16 steps per 32-wide buffer
      int ko = ((s*2 + khalf) ^ swz) * 8;
      half8 a[2], bf[2];
      #pragma unroll
      for (int i = 0; i < 2; ++i) a[i]  = *(const half8*)&sA[cur][(rw*64 + i*32 + l31)*32 + ko];
      #pragma unroll
      for (int j = 0; j < 2; ++j) bf[j] = *(const half8*)&sB[cur][(cw*64 + j*32 + l31)*32 + ko];
      #pragma unroll
      for (int i = 0; i < 2; ++i)
        #pragma unroll
        for (int j = 0; j < 2; ++j)
          acc[i][j] = __builtin_amdgcn_mfma_f32_32x32x16_f16(a[i], bf[j], acc[i][j], 0, 0, 0);
    }
    __syncthreads();
  }
  // epilogue: write pre-BN h into A16 right half, masked column stats
  #pragma unroll
  for (int jt = 0; jt < 2; ++jt) {
    int col = n0 + cw*64 + jt*32 + l31;
    float bias = b1[col];
    float s = 0.f, ss = 0.f;
    #pragma unroll
    for (int i = 0; i < 2; ++i) {
      #pragma unroll
      for (int rg = 0; rg < 16; ++rg) {
        int rib = i*32 + (rg&3) + 8*(rg>>2) + 4*khalf;   // row within batch (0..63)
        float x = acc[i][jt][rg] + bias;
        Aout[(size_t)(m0 + rw*64 + rib)*1024 + 512 + col] = (f16)x;
        if (i == 0 || rib < K_) { s += x; ss += x*x; }
      }
    }
    s  += __shfl_xor(s, 32);
    ss += __shfl_xor(ss, 32);
    if (lane < 32) { sSum[w][jt*32 + l31] = s; sSS[w][jt*32 + l31] = ss; }
  }
  __syncthreads();
  if (t < 128) {
    int c = t;
    int w0 = 2*(c >> 6), ci = c & 63;
    atomicAdd(&csum[n0 + c], sSum[w0][ci] + sSum[w0+1][ci]);
    atomicAdd(&css[n0 + c],  sSS[w0][ci]  + sSS[w0+1][ci]);
  }
}

// ---------- bnrelu: in-place BN+relu on A16 right half (16384 x 512 f16) ----
// Pad rows (58..63 per batch) get finite garbage; downstream masks rib < K_.
__global__ void bnrelu_kernel(f16* __restrict__ A, const float* __restrict__ csum,
                              const float* __restrict__ css, const float* __restrict__ gamma,
                              const float* __restrict__ beta) {
  int t = threadIdx.x, lane = t & 63, w = t >> 6;
  int col = lane * 8;
  float sc[8], sh[8];
  #pragma unroll
  for (int j = 0; j < 8; ++j) {
    int c = col + j;
    float mu  = csum[c] * (1.0f/M_);
    float var = css[c] * (1.0f/M_) - mu*mu;
    float s   = gamma[c] * rsqrtf(var + 1e-5f);
    sc[j] = s; sh[j] = beta[c] - mu*s;
  }
  int r0 = blockIdx.x * 16 + w;
  #pragma unroll
  for (int i = 0; i < 4; ++i) {
    f16* p = A + (size_t)(r0 + i*4)*1024 + 512 + col;
    uint4 u = *(const uint4*)p;
    half8 v = *(half8*)&u, o;
    #pragma unroll
    for (int j = 0; j < 8; ++j) o[j] = (f16)fmaxf((float)v[j]*sc[j] + sh[j], 0.f);
    *(uint4*)p = *(uint4*)&o;
  }
}

// ---------- fused: C = A16 @ Wcat^T, max over k, + biases (8-wave 256x256) ---
// 256x256 tile, BK=64, 8 waves (2M x 4N), wave tile 128x64 (acc[4][2] 32x32).
// LDS 132KB -> 1 block/CU, 256 blocks = full chip.  Phase-split schedule:
// 4 phases/K-tile {ds_read subtile || stage -> bar -> setprio(1) 8 MFMA
// setprio(0) -> bar}.  Staging shifted EARLY (A-h0@P1, A-h1+B-h0@P2,
// B-h1@P3, none@P4) so the newest load has ~2 MFMA clusters of latency
// cover at the single iter-end vmcnt(0) drain (1 block/CU -> no TLP cover).
__launch_bounds__(512, 2)
__global__ void fused_kernel(const f16* __restrict__ A16, const f16* __restrict__ Wcat,
                             const float* __restrict__ bfc, const float* __restrict__ b2,
                             float* __restrict__ out) {
  __shared__ __align__(16) f16 sA[2][256*64];   // 64 KB
  __shared__ __align__(16) f16 sB[2][256*64];   // 64 KB
  __shared__ float sMax[4][256];                // 4 KB
  int t = threadIdx.x;
  int g = blockIdx.x;                   // 256 blocks: xcd-swizzled
  int xcd = g & 7, rest = g >> 3;
  int nt = rest & 3;                    // 4 e-tiles of 256
  int bt = xcd + 8*(rest >> 2);         // m-tile 0..63 (4 batches each); same-bt same XCD
  int e0 = nt * 256;
  int lane = t & 63, w = t >> 6;
  int l31 = lane & 31, khalf = lane >> 5, swzr = l31 & 7;
  int wm = w >> 2, wn = w & 3;          // wave tile: rows wm*128+, cols wn*64+
  floatx16 acc[4][2] = {};
  const f16* Ab = A16 + (size_t)bt*256*1024;
  const f16* Bb = Wcat + (size_t)e0*1024;
  // LDS read bases (f16 offsets); slot for k-chunk ck is (ck ^ swzr)
  int aBase0 = (wm*128 +  0 + l31)*64;
  int aBase1 = (wm*128 + 32 + l31)*64;
  int aBase2 = (wm*128 + 64 + l31)*64;
  int aBase3 = (wm*128 + 96 + l31)*64;
  int bBase0 = (wn*64  +  0 + l31)*64;
  int bBase1 = (wn*64  + 32 + l31)*64;
  // prologue: tile 0, all 4 halves
  stage_half(Ab, sA[0], 0, w, lane);
  stage_half(Ab, sA[0], 1, w, lane);
  stage_half(Bb, sB[0], 0, w, lane);
  stage_half(Bb, sB[0], 1, w, lane);
  WAIT_VMCNT0(); BAR();
  int cur = 0;
  #pragma unroll 1
  for (int it = 0; it < 16; ++it) {
    int nxt = cur ^ 1;
    const f16* An = Ab + (it+1)*64;
    const f16* Bn = Bb + (it+1)*64;
    const f16* sAc = sA[cur];
    const f16* sBc = sB[cur];
    half8 a0f[4], a1f[4], a2f[4], a3f[4], b0v[4], b1v[4];
    // ---- P1: read a(mf0,mf1)+b(nf0); stage A-half0; MFMA Q(m-lo, n0) ----
    #pragma unroll
    for (int s = 0; s < 4; ++s) {
      int ko = (((s<<1)|khalf) ^ swzr) << 3;
      a0f[s] = *(const half8*)&sAc[aBase0 + ko];
      a1f[s] = *(const half8*)&sAc[aBase1 + ko];
      b0v[s] = *(const half8*)&sBc[bBase0 + ko];
    }
    if (it < 15) stage_half(An, sA[nxt], 0, w, lane);
    BAR(); PRIO1();
    #pragma unroll
    for (int s = 0; s < 4; ++s) {
      acc[0][0] = __builtin_amdgcn_mfma_f32_32x32x16_f16(a0f[s], b0v[s], acc[0][0], 0,0,0);
      acc[1][0] = __builtin_amdgcn_mfma_f32_32x32x16_f16(a1f[s], b0v[s], acc[1][0], 0,0,0);
    }
    PRIO0(); BAR();
    // ---- P2: read b(nf1); stage A-half1 + B-half0; MFMA Q(m-lo, n1) ----
    #pragma unroll
    for (int s = 0; s < 4; ++s) {
      int ko = (((s<<1)|khalf) ^ swzr) << 3;
      b1v[s] = *(const half8*)&sBc[bBase1 + ko];
    }
    if (it < 15) {
      stage_half(An, sA[nxt], 1, w, lane);
      stage_half(Bn, sB[nxt], 0, w, lane);
    }
    BAR(); PRIO1();
    #pragma unroll
    for (int s = 0; s < 4; ++s) {
      acc[0][1] = __builtin_amdgcn_mfma_f32_32x32x16_f16(a0f[s], b1v[s], acc[0][1], 0,0,0);
      acc[1][1] = __builtin_amdgcn_mfma_f32_32x32x16_f16(a1f[s], b1v[s], acc[1][1], 0,0,0);
    }
    PRIO0(); BAR();
    // ---- P3: read a(mf2,mf3); stage B-half1; MFMA Q(m-hi, n1) ----
    #pragma unroll
    for (int s = 0; s < 4; ++s) {
      int ko = (((s<<1)|khalf) ^ swzr) << 3;
      a2f[s] = *(const half8*)&sAc[aBase2 + ko];
      a3f[s] = *(const half8*)&sAc[aBase3 + ko];
    }
    if (it < 15) stage_half(Bn, sB[nxt], 1, w, lane);
    BAR(); PRIO1();
    #pragma unroll
    for (int s = 0; s < 4; ++s) {
      acc[2][1] = __builtin_amdgcn_mfma_f32_32x32x16_f16(a2f[s], b1v[s], acc[2][1], 0,0,0);
      acc[3][1] = __builtin_amdgcn_mfma_f32_32x32x16_f16(a3f[s], b1v[s], acc[3][1], 0,0,0);
    }
    PRIO0(); BAR();
    // ---- P4: no staging; MFMA Q(m-hi, n0); iter-end drain ----
    BAR(); PRIO1();
    #pragma unroll
    for (int s = 0; s < 4; ++s) {
      acc[2][0] = __builtin_amdgcn_mfma_f32_32x32x16_f16(a2f[s], b0v[s], acc[2][0], 0,0,0);
      acc[3][0] = __builtin_amdgcn_mfma_f32_32x32x16_f16(a3f[s], b0v[s], acc[3][0], 0,0,0);
    }
    PRIO0();
    WAIT_VMCNT0();                     // newest stage (B-h1, P3) ~2 clusters old
    BAR();                             // publish; also retires all reads of slot cur
    cur = nxt;
  }
  // epilogue: masked max over 58 real rows of each batch this wave covers
  // C/D 32x32: col = l31, rowin = (rg&3) + 8*(rg>>2) + 4*khalf
  #pragma unroll
  for (int p = 0; p < 2; ++p) {         // batch = wm*2 + p ; frags mf = 2p, 2p+1
    #pragma unroll
    for (int nf = 0; nf < 2; ++nf) {
      float mx = -3.0e38f;
      #pragma unroll
      for (int rg = 0; rg < 16; ++rg)   // mf even: rows 0..31 all < K_
        mx = fmaxf(mx, acc[2*p][nf][rg]);
      #pragma unroll
      for (int rg = 0; rg < 16; ++rg) { // mf odd: rows 32+rowin, need rowin < 26
        int rowin = (rg&3) + 8*(rg>>2) + 4*khalf;
        if (rowin < K_ - 32) mx = fmaxf(mx, acc[2*p+1][nf][rg]);
      }
      mx = fmaxf(mx, __shfl_xor(mx, 32));
      if (lane < 32) sMax[wm*2 + p][wn*64 + nf*32 + l31] = mx;
    }
  }
  __syncthreads();
  #pragma unroll
  for (int j = 0; j < 2; ++j) {
    int idx = t + j*512;                // 1024 outputs: 4 batches x 256 cols
    int bq = idx >> 8, c = idx & 255;
    int e = e0 + c;
    out[((size_t)bt*4 + bq)*E_ + e] = sMax[bq][c] + bfc[e] + b2[e];
  }
}

extern "C" void kernel_launch(void* const* d_in, const int* in_sizes, int n_in,
                              void* d_out, int out_size, void* d_ws, size_t ws_size,
                              hipStream_t stream) {
  const float* emb   = (const float*)d_in[0];
  const float* attn  = (const float*)d_in[1];
  const float* Wfc   = (const float*)d_in[2];
  const float* bfc   = (const float*)d_in[3];
  const float* W1    = (const float*)d_in[4];
  const float* b1    = (const float*)d_in[5];
  const float* gamma = (const float*)d_in[6];
  const float* beta  = (const float*)d_in[7];
  const float* W2    = (const float*)d_in[8];
  const float* b2    = (const float*)d_in[9];
  float* out = (float*)d_out;

  char* ws = (char*)d_ws;
  f16*   A16   = (f16*)(ws);                    // 16384*1024*2 = 33,554,432
  f16*   Wcat  = (f16*)(ws + 33554432);         // 1024*1024*2  =  2,097,152
  f16*   W1_16 = (f16*)(ws + 35651584);         //  512*512*2   =    524,288
  float* csum  = (float*)(ws + 36175872);       // 2048
  float* css   = (float*)(ws + 36177920);       // 2048 (contiguous after csum)

  setup_kernel<<<897, 256, 0, stream>>>(Wfc, W2, W1, attn, emb, Wcat, W1_16, A16, csum);
  gemm1_kernel<<<512, 256, 0, stream>>>(A16, W1_16, b1, A16, csum, css);
  bnrelu_kernel<<<1024, 256, 0, stream>>>(A16, csum, css, gamma, beta);
  fused_kernel<<<256, 512, 0, stream>>>(A16, Wcat, bfc, b2, out);
}